// Round 3
// baseline (503.486 us; speedup 1.0000x reference)
//
#include <hip/hip_runtime.h>

#define Bd 16
#define Cd 512
#define HWd 4096          // 64*64
#define NCLS 5
#define BETA 2.0f
#define EPS2 (0.001f * 0.001f)

// Each block streams a CONTIGUOUS 4-channel slab of one batch:
//   2 tensors x 64 KB fully-sequential reads -> DRAM row-buffer friendly
// (the R2 kernel's 16KB-strided 8-stream pattern ran DRAM at ~38% eff).
constexpr int CHB = 4;              // channels per block
constexpr int NCHUNK = Cd / CHB;    // 128 chunks per batch
constexpr int Q4 = HWd / 4;         // 1024 float4 per channel slice
// grid = (128, 16) = 2048 blocks -> 8 blocks/CU, 32 waves/CU at VGPR<=64

__global__ __launch_bounds__(256, 8) void seg_partial_kernel(
    const float* __restrict__ rec, const float* __restrict__ aln,
    const int* __restrict__ mask,
    float* __restrict__ segsum, float* __restrict__ segcnt)
{
    const int tid   = threadIdx.x;
    const int b     = blockIdx.y;
    const int chunk = blockIdx.x;

    const size_t base = ((size_t)b * Cd + (size_t)chunk * CHB) * HWd;
    const float4* __restrict__ rv = (const float4*)(rec + base);
    const float4* __restrict__ av = (const float4*)(aln + base);
    const int4*   __restrict__ mv = (const int4*)(mask + (size_t)b * HWd);

    // per-pixel-quad diff^2 accumulators; pixel-quads repeat across channels
    float4 acc0 = {0,0,0,0}, acc1 = {0,0,0,0}, acc2 = {0,0,0,0}, acc3 = {0,0,0,0};

#pragma unroll
    for (int c = 0; c < CHB; ++c) {
        const float4* r4 = rv + c * Q4;
        const float4* a4 = av + c * Q4;
        float4 r0 = r4[tid], r1 = r4[tid + 256], r2 = r4[tid + 512], r3 = r4[tid + 768];
        float4 a0 = a4[tid], a1 = a4[tid + 256], a2 = a4[tid + 512], a3 = a4[tid + 768];
        float d;
        d = r0.x - a0.x; acc0.x += d * d;
        d = r0.y - a0.y; acc0.y += d * d;
        d = r0.z - a0.z; acc0.z += d * d;
        d = r0.w - a0.w; acc0.w += d * d;
        d = r1.x - a1.x; acc1.x += d * d;
        d = r1.y - a1.y; acc1.y += d * d;
        d = r1.z - a1.z; acc1.z += d * d;
        d = r1.w - a1.w; acc1.w += d * d;
        d = r2.x - a2.x; acc2.x += d * d;
        d = r2.y - a2.y; acc2.y += d * d;
        d = r2.z - a2.z; acc2.z += d * d;
        d = r2.w - a2.w; acc2.w += d * d;
        d = r3.x - a3.x; acc3.x += d * d;
        d = r3.y - a3.y; acc3.y += d * d;
        d = r3.z - a3.z; acc3.z += d * d;
        d = r3.w - a3.w; acc3.w += d * d;
    }

    // mask loaded AFTER the stream loop (L2-hot, keeps live VGPRs < 64)
    int4 m0 = mv[tid];
    int4 m1 = mv[tid + 256];
    int4 m2 = mv[tid + 512];
    int4 m3 = mv[tid + 768];

    // per-thread class accumulators (predication amortized over CHB channels)
    float cls[NCLS] = {0, 0, 0, 0, 0};
    {
        float v[16] = {acc0.x, acc0.y, acc0.z, acc0.w,
                       acc1.x, acc1.y, acc1.z, acc1.w,
                       acc2.x, acc2.y, acc2.z, acc2.w,
                       acc3.x, acc3.y, acc3.z, acc3.w};
        int   mm[16] = {m0.x, m0.y, m0.z, m0.w,
                        m1.x, m1.y, m1.z, m1.w,
                        m2.x, m2.y, m2.z, m2.w,
                        m3.x, m3.y, m3.z, m3.w};
#pragma unroll
        for (int e = 0; e < 16; ++e) {
#pragma unroll
            for (int k = 0; k < NCLS; ++k)
                cls[k] += (mm[e] == k) ? v[e] : 0.0f;
        }
    }

    // wave-level butterfly reduce (64 lanes), then 5 global atomics per wave
#pragma unroll
    for (int k = 0; k < NCLS; ++k) {
#pragma unroll
        for (int off = 32; off > 0; off >>= 1)
            cls[k] += __shfl_down(cls[k], off, 64);
    }
    if ((tid & 63) == 0) {
        const float scale = 1.0f / (float)Cd;   // channel mean
#pragma unroll
        for (int k = 0; k < NCLS; ++k)
            atomicAdd(&segsum[b * NCLS + k], cls[k] * scale);
    }

    // counts: chunk-0 blocks already hold the full mask of their batch
    if (chunk == 0) {
        float cnt[NCLS] = {0, 0, 0, 0, 0};
        int mm[16] = {m0.x, m0.y, m0.z, m0.w,
                      m1.x, m1.y, m1.z, m1.w,
                      m2.x, m2.y, m2.z, m2.w,
                      m3.x, m3.y, m3.z, m3.w};
#pragma unroll
        for (int e = 0; e < 16; ++e) {
#pragma unroll
            for (int k = 0; k < NCLS; ++k)
                cnt[k] += (mm[e] == k) ? 1.0f : 0.0f;
        }
#pragma unroll
        for (int k = 0; k < NCLS; ++k) {
#pragma unroll
            for (int off = 32; off > 0; off >>= 1)
                cnt[k] += __shfl_down(cnt[k], off, 64);
        }
        if ((tid & 63) == 0) {
#pragma unroll
            for (int k = 0; k < NCLS; ++k)
                atomicAdd(&segcnt[b * NCLS + k], cnt[k]);
        }
    }
}

// Kernel 2: 80 segments -> scalar. One block of 128 threads.
__global__ __launch_bounds__(128) void finalize_kernel(
    const float* __restrict__ segsum, const float* __restrict__ segcnt,
    float* __restrict__ out)
{
    __shared__ float sMax[128];
    __shared__ float sSum[128];
    const int t = threadIdx.x;

    float s = 0.0f, cnt = 0.0f;
    if (t < Bd * NCLS) { s = segsum[t]; cnt = segcnt[t]; }
    const float avg = s / fmaxf(cnt, 1.0f);   // empty segments -> 0 (contribute nothing)

    sMax[t] = avg;
    __syncthreads();
#pragma unroll
    for (int off = 64; off > 0; off >>= 1) {
        if (t < off) sMax[t] = fmaxf(sMax[t], sMax[t + off]);
        __syncthreads();
    }
    const float wmax = sMax[0];

    float w = (wmax > 0.0f) ? (avg / (wmax + EPS2)) : (avg + EPS2);
    w = fminf(fmaxf(w, 0.0f), 1.0f);

    sSum[t] = s * (w * BETA + 1.0f);
    __syncthreads();
#pragma unroll
    for (int off = 64; off > 0; off >>= 1) {
        if (t < off) sSum[t] += sSum[t + off];
        __syncthreads();
    }
    if (t == 0) out[0] = sSum[0] / (float)(Bd * HWd);
}

extern "C" void kernel_launch(void* const* d_in, const int* in_sizes, int n_in,
                              void* d_out, int out_size, void* d_ws, size_t ws_size,
                              hipStream_t stream) {
    const float* rec  = (const float*)d_in[0];
    const float* aln  = (const float*)d_in[1];
    const int*   mask = (const int*)d_in[2];
    float* out = (float*)d_out;

    float* segsum = (float*)d_ws;
    float* segcnt = segsum + Bd * NCLS;

    // zero the 2*80 accumulators (ws is re-poisoned to 0xAA before every launch)
    hipMemsetAsync(d_ws, 0, 2 * Bd * NCLS * sizeof(float), stream);

    dim3 grid(NCHUNK, Bd);   // (128, 16) = 2048 blocks, each a contiguous 2x64KB slab
    seg_partial_kernel<<<grid, 256, 0, stream>>>(rec, aln, mask, segsum, segcnt);
    finalize_kernel<<<1, 128, 0, stream>>>(segsum, segcnt, out);
}